// Round 1
// baseline (892.416 us; speedup 1.0000x reference)
//
#include <hip/hip_runtime.h>
#include <hip/hip_bf16.h>

#define BROWS 131072
#define HD 128

typedef __attribute__((ext_vector_type(8))) short bf16x8;
typedef __attribute__((ext_vector_type(4))) float f32x4;

static __device__ __forceinline__ unsigned short f2bf(float f) {
    union { float f; unsigned int i; } v;
    v.f = f;
    unsigned int u = v.i;
    u += 0x7FFFu + ((u >> 16) & 1u);
    return (unsigned short)(u >> 16);
}
static __device__ __forceinline__ float fast_sigmoid(float x) {
    float e = __builtin_amdgcn_exp2f(-1.442695040888963f * x);
    return __builtin_amdgcn_rcpf(1.0f + e);
}
static __device__ __forceinline__ float fast_tanh(float x) {
    float e = __builtin_amdgcn_exp2f(2.885390081777927f * x);
    return 1.0f - 2.0f * __builtin_amdgcn_rcpf(1.0f + e);
}

// Convert 8 consecutive f32 (16B-aligned) to a bf16x8 fragment
// (packed v_cvt_pk_bf16_f32 on gfx950).
static __device__ __forceinline__ bf16x8 cvt8(const float* p) {
    f32x4 a = ((const f32x4*)p)[0];
    f32x4 b = ((const f32x4*)p)[1];
    __hip_bfloat162 r0 = __float22bfloat162_rn(float2{a[0], a[1]});
    __hip_bfloat162 r1 = __float22bfloat162_rn(float2{a[2], a[3]});
    __hip_bfloat162 r2 = __float22bfloat162_rn(float2{b[0], b[1]});
    __hip_bfloat162 r3 = __float22bfloat162_rn(float2{b[2], b[3]});
    union { __hip_bfloat162 h2; unsigned int u; } u0, u1, u2, u3;
    u0.h2 = r0; u1.h2 = r1; u2.h2 = r2; u3.h2 = r3;
    union { unsigned int u[4]; bf16x8 v; } out;
    out.u[0] = u0.u; out.u[1] = u1.u; out.u[2] = u2.u; out.u[3] = u3.u;
    return out.v;
}

// Pack weights (f32, [k][n] row-major, 128x128 each) into bf16
// pack[(g*128 + n)*256 + k];  k<128 -> input-weight row k, k>=128 -> hidden
// weight row k-128. n = s*16+nl, so slice s of gate g is the contiguous
// 8 KB region pack + ((g*8+s)*16)*256. Total 256 KB -> L2-resident.
// Read side coalesced: n is the fastest index over threads.
__global__ void pack_weights(const float* __restrict__ w_ii,
                             const float* __restrict__ w_if,
                             const float* __restrict__ w_ig,
                             const float* __restrict__ w_io,
                             const float* __restrict__ w_hi,
                             const float* __restrict__ w_hf,
                             const float* __restrict__ w_hg,
                             const float* __restrict__ w_ho,
                             unsigned short* __restrict__ pack) {
    int idx = blockIdx.x * 256 + threadIdx.x;   // 0 .. 131071
    int n = idx & 127;
    int k = (idx >> 7) & 255;
    int g = idx >> 15;
    const float* wx = (g == 0) ? w_ii : (g == 1) ? w_if : (g == 2) ? w_ig : w_io;
    const float* wh = (g == 0) ? w_hi : (g == 1) ? w_hf : (g == 2) ? w_hg : w_ho;
    float v = (k < 128) ? wx[k * 128 + n] : wh[(k - 128) * 128 + n];
    pack[(g * 128 + n) * 256 + k] = f2bf(v);
}

// grid(2048), 512 threads (8 waves).
// Each block owns a 64-row tile and ALL 128 output columns: wave w owns the
// 16-col slice s = w of each of the 4 gates -> acc[4 m-tiles][4 gates].
// A-tile (64 rows x 256 k, bf16) staged once in 32 KB LDS, shared by 8 waves
// (no more duplicate staging across a column-split).
// __launch_bounds__(512, 8): 4 blocks/CU * 8 waves = 32 waves/CU (100% occ)
// vs previous 12 waves/CU -- this kernel is latency-bound, not BW-bound.
// B fragments read per-K-step from the 256 KB packed weights (L2-resident).
__global__ __launch_bounds__(512, 8)
void lstm_main(const float* __restrict__ x,
               const float* __restrict__ h_prev,
               const float* __restrict__ c_prev,
               const unsigned short* __restrict__ pack,
               const float* __restrict__ b_i,
               const float* __restrict__ b_f,
               const float* __restrict__ b_g,
               const float* __restrict__ b_o,
               float* __restrict__ out) {
    __shared__ bf16x8 alds8[2048];                // 32 KB
    unsigned short* alds = (unsigned short*)alds8;

    const int tid  = threadIdx.x;
    const int row0 = blockIdx.x * 64;
    const int wid  = tid >> 6;                    // 0..7
    const int lane = tid & 63;
    const int ml   = lane & 15;
    const int q    = lane >> 4;                   // 0..3
    const int s    = wid;                         // 16-col slice 0..7

    // ---- stage A tile: 64 rows x 256 k (x | h_prev), f32 -> bf16 ----
    // chunk c: row = c>>5, kc = c&31 (8 k each); swizzle kc by row&7.
    #pragma unroll
    for (int i = 0; i < 4; ++i) {
        int c   = i * 512 + tid;
        int row = c >> 5;
        int kc  = c & 31;
        const float* src = (kc < 16) ? (x + (size_t)(row0 + row) * 128 + kc * 8)
                                     : (h_prev + (size_t)(row0 + row) * 128 + (kc - 16) * 8);
        bf16x8 v = cvt8(src);
        *((bf16x8*)&alds[row * 256 + (kc ^ (row & 7)) * 8]) = v;
    }
    __syncthreads();

    f32x4 acc[4][4];   // [m-tile][gate]
    #pragma unroll
    for (int mt = 0; mt < 4; ++mt)
        #pragma unroll
        for (int g = 0; g < 4; ++g)
            acc[mt][g] = (f32x4){0.f, 0.f, 0.f, 0.f};

    const unsigned short* pbase = pack + ((size_t)s * 16 + ml) * 256 + q * 8;

    // ---- K loop: 8 steps of K=32 ----
    #pragma unroll 2
    for (int ks = 0; ks < 8; ++ks) {
        bf16x8 a[4];
        #pragma unroll
        for (int mt = 0; mt < 4; ++mt) {
            int rowl = mt * 16 + ml;
            int kcs  = (ks * 4 + q) ^ (ml & 7);
            a[mt] = *(const bf16x8*)(&alds[rowl * 256 + kcs * 8]);
        }

        bf16x8 b[4];
        #pragma unroll
        for (int g = 0; g < 4; ++g)
            b[g] = *(const bf16x8*)(pbase + (size_t)g * 8 * 16 * 256 + ks * 32);

        #pragma unroll
        for (int mt = 0; mt < 4; ++mt)
            #pragma unroll
            for (int g = 0; g < 4; ++g)
                acc[mt][g] = __builtin_amdgcn_mfma_f32_16x16x32_bf16(
                    a[mt], b[g], acc[mt][g], 0, 0, 0);
    }

    // ---- epilogue (f32 outputs) ----
    const int col = s * 16 + ml;                  // 0..127
    float bi = b_i[col], bf_ = b_f[col], bg = b_g[col], bo = b_o[col];

    float* out_h = out;
    float* out_c = out + (size_t)BROWS * HD;

    #pragma unroll
    for (int mt = 0; mt < 4; ++mt) {
        #pragma unroll
        for (int r = 0; r < 4; ++r) {
            int row = row0 + mt * 16 + q * 4 + r;
            float ai = acc[mt][0][r] + bi;
            float af = acc[mt][1][r] + bf_;
            float ag = acc[mt][2][r] + bg;
            float ao = acc[mt][3][r] + bo;
            float ig = fast_sigmoid(ai);
            float fg = fast_sigmoid(af);
            float gg = fast_tanh(ag);
            float og = fast_sigmoid(ao);
            float cp = c_prev[(size_t)row * 128 + col];
            float cv = fg * cp + ig * gg;
            float hv = og * fast_tanh(cv);
            out_h[(size_t)row * 128 + col] = hv;
            out_c[(size_t)row * 128 + col] = cv;
        }
    }
}

extern "C" void kernel_launch(void* const* d_in, const int* in_sizes, int n_in,
                              void* d_out, int out_size, void* d_ws, size_t ws_size,
                              hipStream_t stream) {
    const float* x  = (const float*)d_in[0];
    const float* h  = (const float*)d_in[1];
    const float* c  = (const float*)d_in[2];
    unsigned short* pack = (unsigned short*)d_ws;   // 256 KB

    pack_weights<<<512, 256, 0, stream>>>(
        (const float*)d_in[3], (const float*)d_in[4],
        (const float*)d_in[5], (const float*)d_in[6],
        (const float*)d_in[7], (const float*)d_in[8],
        (const float*)d_in[9], (const float*)d_in[10],
        pack);

    dim3 grid(BROWS / 64);
    lstm_main<<<grid, 512, 0, stream>>>(
        x, h, c, pack,
        (const float*)d_in[11], (const float*)d_in[12],
        (const float*)d_in[13], (const float*)d_in[14],
        (float*)d_out);
}

// Round 2
// 340.475 us; speedup vs baseline: 2.6211x; 2.6211x over previous
//
#include <hip/hip_runtime.h>
#include <hip/hip_bf16.h>

#define BROWS 131072
#define HD 128

typedef __attribute__((ext_vector_type(8))) short bf16x8;
typedef __attribute__((ext_vector_type(4))) float f32x4;

static __device__ __forceinline__ unsigned short f2bf(float f) {
    union { float f; unsigned int i; } v;
    v.f = f;
    unsigned int u = v.i;
    u += 0x7FFFu + ((u >> 16) & 1u);
    return (unsigned short)(u >> 16);
}
static __device__ __forceinline__ float fast_sigmoid(float x) {
    float e = __builtin_amdgcn_exp2f(-1.442695040888963f * x);
    return __builtin_amdgcn_rcpf(1.0f + e);
}
static __device__ __forceinline__ float fast_tanh(float x) {
    float e = __builtin_amdgcn_exp2f(2.885390081777927f * x);
    return 1.0f - 2.0f * __builtin_amdgcn_rcpf(1.0f + e);
}

// Convert 8 consecutive f32 (16B-aligned) to a bf16x8 fragment
// (packed v_cvt_pk_bf16_f32 on gfx950).
static __device__ __forceinline__ bf16x8 cvt8(const float* p) {
    f32x4 a = ((const f32x4*)p)[0];
    f32x4 b = ((const f32x4*)p)[1];
    __hip_bfloat162 r0 = __float22bfloat162_rn(float2{a[0], a[1]});
    __hip_bfloat162 r1 = __float22bfloat162_rn(float2{a[2], a[3]});
    __hip_bfloat162 r2 = __float22bfloat162_rn(float2{b[0], b[1]});
    __hip_bfloat162 r3 = __float22bfloat162_rn(float2{b[2], b[3]});
    union { __hip_bfloat162 h2; unsigned int u; } u0, u1, u2, u3;
    u0.h2 = r0; u1.h2 = r1; u2.h2 = r2; u3.h2 = r3;
    union { unsigned int u[4]; bf16x8 v; } out;
    out.u[0] = u0.u; out.u[1] = u1.u; out.u[2] = u2.u; out.u[3] = u3.u;
    return out.v;
}

// Pack weights (f32, [k][n] row-major, 128x128 each) into bf16
// pack[(g*128 + n)*256 + k];  k<128 -> input-weight row k, k>=128 -> hidden
// weight row k-128. n = s*16+nl, so slice s of gate g is the contiguous
// 8 KB region pack + ((g*8+s)*16)*256. Total 256 KB -> L2-resident.
// Read side coalesced: n is the fastest index over threads.
__global__ void pack_weights(const float* __restrict__ w_ii,
                             const float* __restrict__ w_if,
                             const float* __restrict__ w_ig,
                             const float* __restrict__ w_io,
                             const float* __restrict__ w_hi,
                             const float* __restrict__ w_hf,
                             const float* __restrict__ w_hg,
                             const float* __restrict__ w_ho,
                             unsigned short* __restrict__ pack) {
    int idx = blockIdx.x * 256 + threadIdx.x;   // 0 .. 131071
    int n = idx & 127;
    int k = (idx >> 7) & 255;
    int g = idx >> 15;
    const float* wx = (g == 0) ? w_ii : (g == 1) ? w_if : (g == 2) ? w_ig : w_io;
    const float* wh = (g == 0) ? w_hi : (g == 1) ? w_hf : (g == 2) ? w_hg : w_ho;
    float v = (k < 128) ? wx[k * 128 + n] : wh[(k - 128) * 128 + n];
    pack[(g * 128 + n) * 256 + k] = f2bf(v);
}

// grid(2048), 512 threads (8 waves).
// Each block owns a 64-row tile and ALL 128 output columns: wave w owns the
// 16-col slice s = w of each of the 4 gates -> acc[4 m-tiles][4 gates].
// A-tile (64 rows x 256 k, bf16) staged once in 32 KB LDS, shared by 8 waves.
//
// __launch_bounds__(512, 4): register cap = 512/4 = 128 regs/lane; this
// kernel needs ~124 (60 VGPR + 64 AGPR acc) -> fits with ZERO spill.
// (512, 8) capped at 64 and spilled the accumulators to scratch: 2.6 GB of
// HBM spill traffic, 706 us. 4 waves/EU is the true register-file ceiling.
// -> 2 blocks/CU x 8 waves = 16 waves/CU (vs 12 in the gx-split version),
// LDS 64 KB/CU of 160 KB.
__global__ __launch_bounds__(512, 4)
void lstm_main(const float* __restrict__ x,
               const float* __restrict__ h_prev,
               const float* __restrict__ c_prev,
               const unsigned short* __restrict__ pack,
               const float* __restrict__ b_i,
               const float* __restrict__ b_f,
               const float* __restrict__ b_g,
               const float* __restrict__ b_o,
               float* __restrict__ out) {
    __shared__ bf16x8 alds8[2048];                // 32 KB
    unsigned short* alds = (unsigned short*)alds8;

    const int tid  = threadIdx.x;
    const int row0 = blockIdx.x * 64;
    const int wid  = tid >> 6;                    // 0..7
    const int lane = tid & 63;
    const int ml   = lane & 15;
    const int q    = lane >> 4;                   // 0..3
    const int s    = wid;                         // 16-col slice 0..7

    // ---- stage A tile: 64 rows x 256 k (x | h_prev), f32 -> bf16 ----
    // chunk c: row = c>>5, kc = c&31 (8 k each); swizzle kc by row&7.
    #pragma unroll
    for (int i = 0; i < 4; ++i) {
        int c   = i * 512 + tid;
        int row = c >> 5;
        int kc  = c & 31;
        const float* src = (kc < 16) ? (x + (size_t)(row0 + row) * 128 + kc * 8)
                                     : (h_prev + (size_t)(row0 + row) * 128 + (kc - 16) * 8);
        bf16x8 v = cvt8(src);
        *((bf16x8*)&alds[row * 256 + (kc ^ (row & 7)) * 8]) = v;
    }
    __syncthreads();

    f32x4 acc[4][4];   // [m-tile][gate]
    #pragma unroll
    for (int mt = 0; mt < 4; ++mt)
        #pragma unroll
        for (int g = 0; g < 4; ++g)
            acc[mt][g] = (f32x4){0.f, 0.f, 0.f, 0.f};

    const unsigned short* pbase = pack + ((size_t)s * 16 + ml) * 256 + q * 8;

    // ---- K loop: 8 steps of K=32 ----
    #pragma unroll 2
    for (int ks = 0; ks < 8; ++ks) {
        bf16x8 a[4];
        #pragma unroll
        for (int mt = 0; mt < 4; ++mt) {
            int rowl = mt * 16 + ml;
            int kcs  = (ks * 4 + q) ^ (ml & 7);
            a[mt] = *(const bf16x8*)(&alds[rowl * 256 + kcs * 8]);
        }

        bf16x8 b[4];
        #pragma unroll
        for (int g = 0; g < 4; ++g)
            b[g] = *(const bf16x8*)(pbase + (size_t)g * 8 * 16 * 256 + ks * 32);

        #pragma unroll
        for (int mt = 0; mt < 4; ++mt)
            #pragma unroll
            for (int g = 0; g < 4; ++g)
                acc[mt][g] = __builtin_amdgcn_mfma_f32_16x16x32_bf16(
                    a[mt], b[g], acc[mt][g], 0, 0, 0);
    }

    // ---- epilogue (f32 outputs) ----
    const int col = s * 16 + ml;                  // 0..127
    float bi = b_i[col], bf_ = b_f[col], bg = b_g[col], bo = b_o[col];

    float* out_h = out;
    float* out_c = out + (size_t)BROWS * HD;

    #pragma unroll
    for (int mt = 0; mt < 4; ++mt) {
        #pragma unroll
        for (int r = 0; r < 4; ++r) {
            int row = row0 + mt * 16 + q * 4 + r;
            float ai = acc[mt][0][r] + bi;
            float af = acc[mt][1][r] + bf_;
            float ag = acc[mt][2][r] + bg;
            float ao = acc[mt][3][r] + bo;
            float ig = fast_sigmoid(ai);
            float fg = fast_sigmoid(af);
            float gg = fast_tanh(ag);
            float og = fast_sigmoid(ao);
            float cp = c_prev[(size_t)row * 128 + col];
            float cv = fg * cp + ig * gg;
            float hv = og * fast_tanh(cv);
            out_h[(size_t)row * 128 + col] = hv;
            out_c[(size_t)row * 128 + col] = cv;
        }
    }
}

extern "C" void kernel_launch(void* const* d_in, const int* in_sizes, int n_in,
                              void* d_out, int out_size, void* d_ws, size_t ws_size,
                              hipStream_t stream) {
    const float* x  = (const float*)d_in[0];
    const float* h  = (const float*)d_in[1];
    const float* c  = (const float*)d_in[2];
    unsigned short* pack = (unsigned short*)d_ws;   // 256 KB

    pack_weights<<<512, 256, 0, stream>>>(
        (const float*)d_in[3], (const float*)d_in[4],
        (const float*)d_in[5], (const float*)d_in[6],
        (const float*)d_in[7], (const float*)d_in[8],
        (const float*)d_in[9], (const float*)d_in[10],
        pack);

    dim3 grid(BROWS / 64);
    lstm_main<<<grid, 512, 0, stream>>>(
        x, h, c, pack,
        (const float*)d_in[11], (const float*)d_in[12],
        (const float*)d_in[13], (const float*)d_in[14],
        (float*)d_out);
}